// Round 17
// baseline (206.358 us; speedup 1.0000x reference)
//
#include <hip/hip_runtime.h>
#include <hip/hip_bf16.h>
#include <cstdint>
#include <cstddef>

#define E_TOT 32768
#define HD    512
#define NR    3
#define EPAD_MAX 33152          // E_TOT + 3*128
#define NTM   259               // EPAD_MAX / 128
#define NB    1036              // NTM * 4 N-tiles (BN=128)
#define NB2   2072              // paired S1

typedef __attribute__((ext_vector_type(8))) short short8;
typedef __attribute__((ext_vector_type(4))) float f32x4;
typedef __attribute__((ext_vector_type(4))) unsigned int u32x4;

static __device__ __forceinline__ unsigned short f2bf(float f) {
  union { float f; unsigned int u; } x; x.f = f;
  unsigned int u = x.u;
  return (unsigned short)((u + 0x7fffu + ((u >> 16) & 1u)) >> 16);  // RNE
}
static __device__ __forceinline__ float bf2f(unsigned short h) {
  union { unsigned int u; float f; } x; x.u = ((unsigned int)h) << 16;
  return x.f;
}
// pair conversion via header intrinsic (RNE) -> compiler emits v_cvt_pk_bf16_f32
static __device__ __forceinline__ unsigned int pk2(float lo, float hi) {
  __hip_bfloat162 h2 = __float22bfloat162_rn(make_float2(lo, hi));
  union { __hip_bfloat162 h; unsigned int u; } c; c.h = h2;
  return c.u;
}

static __device__ __forceinline__ void gload_lds16(const void* g, void* l) {
  __builtin_amdgcn_global_load_lds(
      (const __attribute__((address_space(1))) unsigned int*)g,
      (__attribute__((address_space(3))) unsigned int*)l, 16, 0, 0);
}

// bijective chunked XCD swizzle (m204)
template <int NWG>
static __device__ __forceinline__ int chunk_swz(int bid) {
  constexpr int q = NWG / 8, r = NWG % 8;
  const int x = bid & 7, i = bid >> 3;
  return (x < r) ? x * (q + 1) + i : r * (q + 1) + (x - r) * q + i;
}

// ---------------- prep kernels ----------------

#define AL128(x) (((x) + 127) & ~127)

__global__ void k_sort1(const int* __restrict__ roles, int* __restrict__ ctrl) {
  __shared__ int cnt[NR];
  const int t = threadIdx.x;
  if (t < NR) cnt[t] = 0;
  __syncthreads();
  int c0 = 0, c1 = 0, c2 = 0;
  for (int i = t; i < E_TOT; i += 1024) {
    const int ro = roles[i];
    c0 += (ro == 0); c1 += (ro == 1); c2 += (ro == 2);
  }
  if (c0) atomicAdd(&cnt[0], c0);
  if (c1) atomicAdd(&cnt[1], c1);
  if (c2) atomicAdd(&cnt[2], c2);
  __syncthreads();
  if (t == 0) {
    const int off1 = AL128(cnt[0]);
    const int off2 = AL128(off1 + cnt[1]);
    const int ptot = AL128(off2 + cnt[2]);
    ctrl[0] = cnt[0]; ctrl[1] = cnt[1]; ctrl[2] = cnt[2];
    ctrl[4] = 0; ctrl[5] = off1; ctrl[6] = off2; ctrl[7] = ptot;
    ctrl[9] = 0; ctrl[10] = off1; ctrl[11] = off2;
  }
}

__global__ void k_scatter(const int* __restrict__ roles, int* __restrict__ ctrl,
                          int* __restrict__ perm) {
  int e = blockIdx.x * 256 + threadIdx.x;
  int lane = threadIdx.x & 63;
  int role = roles[e];
#pragma unroll
  for (int r = 0; r < NR; ++r) {
    unsigned long long m = __ballot(role == r);
    if (!m) continue;
    int leader = __ffsll((unsigned long long)m) - 1;
    int base = 0;
    if (lane == leader) base = atomicAdd(&ctrl[9 + r], (int)__popcll(m));
    base = __shfl(base, leader);
    if (role == r) {
      int rank = (int)__popcll(m & ((1ull << lane) - 1ull));
      perm[base + rank] = e;
    }
  }
}

// fill pad slots through EPAD_MAX so every perm read is valid
__global__ void k_padfill(const int* __restrict__ ctrl, int* __restrict__ perm) {
#pragma unroll
  for (int r = 0; r < NR; ++r) {
    const int start = ctrl[4 + r] + ctrl[r];
    const int end = (r < 2) ? ctrl[5 + r] : EPAD_MAX;
    const int fill = (ctrl[r] > 0) ? perm[ctrl[4 + r]] : 0;
    for (int i = start + (int)threadIdx.x; i < end; i += 256) perm[i] = fill;
  }
}

__global__ void k_convw(const float* __restrict__ W, const float* __restrict__ U,
                        const float* __restrict__ P1, const float* __restrict__ P2,
                        const int* __restrict__ dlayer, short* __restrict__ dst) {
  const int per = NR * HD * HD;
  const int which = blockIdx.y;
  const float* src = (which == 0) ? W : (which == 1) ? U : (which == 2) ? P1 : P2;
  src += (size_t)dlayer[0] * per;
  short* d = dst + (size_t)which * per;
  int i = (blockIdx.x * 256 + threadIdx.x) * 4;
  if (i >= per) return;
  float4 v = *(const float4*)(src + i);
  uint2 o;
  o.x = pk2(v.x, v.y);
  o.y = pk2(v.z, v.w);
  *(uint2*)(d + i) = o;
}

// ---------------- m97-style GEMM (R16 core + cvt_pk staging) ----------------
// BM=BN=128, BK=64. 256 thr = 4 waves (2M x 2N), wave tile 64x64.
// acc[4][4] f32x4 = 64 floats. LDS = As+Bs 32KB (single buffer).
// NO launch_bounds min-waves (R13 lesson). R14: 96 VGPR no-spill, ~4 blk/CU.
// R15 (dbuf+vmcnt) NULL -> within-block latency covered by cross-block TLP.
// R16 lesson: manual f2bf bit-twiddle defeats v_cvt_pk_bf16_f32 pattern-match
// (VALUBusy 21%); this round uses __float22bfloat162_rn pairs in staging.
// XOR swizzle: LDS[row][us] holds data-unit us^(row&7); sources pre-swizzled,
// reads XOR'd (R5-verified 0-conflict). D-frag: col=lane&15, row=(lane>>4)*4+reg.
//
// AM 0: A bf16 rows via global_load_lds.
// AM 1: A = A0*A1 bf16 product, reg-staged (T14).
// AM 2: A = f32 gather via perm + cvt_pk convert, reg-staged.
// OM 0: bf16 + bias. OM 1: bf16 + bias + relu. OM 2: f32 perm-scatter.
template <int AM, int OM, int PAIRED>
__global__ __launch_bounds__(256) void k_mm(
    const void* __restrict__ A0, const void* __restrict__ A1,
    const short* __restrict__ B0, const short* __restrict__ B1,
    const float* __restrict__ bias0, const float* __restrict__ bias1,
    const int* __restrict__ dlayer, const int* __restrict__ ctrl,
    const int* __restrict__ perm, short* __restrict__ outS0,
    short* __restrict__ outS1, float* __restrict__ outF) {
  __shared__ short As[128 * 64];
  __shared__ short Bs[128 * 64];

  int lb = chunk_swz<PAIRED ? NB2 : NB>(blockIdx.x);
  int pair = 0;
  if constexpr (PAIRED) { pair = lb >= NB ? 1 : 0; lb -= pair * NB; }
  const int m0 = (lb >> 2) * 128, n0 = (lb & 3) * 128;
  if (m0 >= ctrl[7]) return;
  const int role = (m0 >= ctrl[6]) ? 2 : (m0 >= ctrl[5] ? 1 : 0);

  const int tid = threadIdx.x;
  const int lane = tid & 63;
  const int wv = tid >> 6;
  const int wr = wv >> 1, wc = wv & 1;
  const int krow = lane & 15, ku = lane >> 4;

  const short* Brole = (PAIRED && pair ? B1 : B0) + (size_t)role * HD * HD;
  const short* Abf = (const short*)((PAIRED && pair) ? A1 : A0);
  const float* Af32 = (const float*)((PAIRED && pair) ? A1 : A0);

  // staging: g = j*256+tid; row=g>>3; storage-unit us=g&7 holds data-unit
  // ud = us ^ (row&7); source pre-swizzled accordingly.
  unsigned asrc[4], bsrc[4];
#pragma unroll
  for (int j = 0; j < 4; ++j) {
    const int g = j * 256 + tid;
    const int row = g >> 3;
    const int ud = (g & 7) ^ (row & 7);
    if constexpr (AM == 2)
      asrc[j] = (unsigned)perm[m0 + row] * HD + ud * 8;   // gathered f32 row
    else
      asrc[j] = (unsigned)(m0 + row) * HD + ud * 8;
    bsrc[j] = (unsigned)(n0 + row) * HD + ud * 8;
  }

  f32x4 acc[4][4];
#pragma unroll
  for (int a = 0; a < 4; ++a)
#pragma unroll
    for (int b = 0; b < 4; ++b) acc[a][b] = (f32x4)0.f;

  for (int t = 0; t < 8; ++t) {
    const int k0 = t * 64;
    // ---- stage ----
#pragma unroll
    for (int j = 0; j < 4; ++j)
      gload_lds16(Brole + (size_t)bsrc[j] + k0, &Bs[(j * 256 + tid) * 8]);
    if constexpr (AM == 0) {
#pragma unroll
      for (int j = 0; j < 4; ++j)
        gload_lds16(Abf + (size_t)asrc[j] + k0, &As[(j * 256 + tid) * 8]);
    } else if constexpr (AM == 1) {
#pragma unroll
      for (int j = 0; j < 4; ++j) {
        const short8 av = *(const short8*)((const short*)A0 + (size_t)asrc[j] + k0);
        const short8 ar = *(const short8*)((const short*)A1 + (size_t)asrc[j] + k0);
        u32x4 o;
#pragma unroll
        for (int e = 0; e < 4; ++e) {
          const float p0 = bf2f((unsigned short)av[2 * e]) *
                           bf2f((unsigned short)ar[2 * e]);
          const float p1 = bf2f((unsigned short)av[2 * e + 1]) *
                           bf2f((unsigned short)ar[2 * e + 1]);
          o[e] = pk2(p0, p1);
        }
        *(u32x4*)&As[(j * 256 + tid) * 8] = o;
      }
    } else {
      // AM 2: gather f32 rows via perm, cvt_pk convert, ds_write
#pragma unroll
      for (int j = 0; j < 4; ++j) {
        const float* s = Af32 + (size_t)asrc[j] + k0;
        const float4 x0 = *(const float4*)s;
        const float4 x1 = *(const float4*)(s + 4);
        u32x4 o;
        o[0] = pk2(x0.x, x0.y);
        o[1] = pk2(x0.z, x0.w);
        o[2] = pk2(x1.x, x1.y);
        o[3] = pk2(x1.z, x1.w);
        *(u32x4*)&As[(j * 256 + tid) * 8] = o;
      }
    }
    __syncthreads();   // drains gload_lds + ds_write
    // ---- compute ----
    short8 fa[4][2], fb[4][2];
#pragma unroll
    for (int mi = 0; mi < 4; ++mi)
#pragma unroll
      for (int ks = 0; ks < 2; ++ks) {
        const int row = wr * 64 + mi * 16 + krow;
        fa[mi][ks] = *(const short8*)&As[row * 64 + (((ks * 4 + ku) ^ (row & 7)) * 8)];
      }
#pragma unroll
    for (int ni = 0; ni < 4; ++ni)
#pragma unroll
      for (int ks = 0; ks < 2; ++ks) {
        const int row = wc * 64 + ni * 16 + krow;
        fb[ni][ks] = *(const short8*)&Bs[row * 64 + (((ks * 4 + ku) ^ (row & 7)) * 8)];
      }
#pragma unroll
    for (int ks = 0; ks < 2; ++ks)
#pragma unroll
      for (int mi = 0; mi < 4; ++mi)
#pragma unroll
        for (int ni = 0; ni < 4; ++ni)
          acc[mi][ni] = __builtin_amdgcn_mfma_f32_16x16x32_bf16(
              fa[mi][ks], fb[ni][ks], acc[mi][ni], 0, 0, 0);
    __syncthreads();   // LDS reads done before next stage
  }

  // ---- epilogue: direct stores ----
  const int ld = dlayer[0];
  const float* bias = (PAIRED && pair ? bias1 : bias0) +
                      ((size_t)ld * NR + role) * HD + n0;
  short* outS = (PAIRED && pair) ? outS1 : outS0;

  int pg[4][4];
  if constexpr (OM == 2) {
#pragma unroll
    for (int mi = 0; mi < 4; ++mi)
#pragma unroll
      for (int j = 0; j < 4; ++j)
        pg[mi][j] = perm[m0 + wr * 64 + mi * 16 + ku * 4 + j];
  }

#pragma unroll
  for (int ni = 0; ni < 4; ++ni) {
    const int col = wc * 64 + ni * 16 + krow;
    const float b = bias[col];
#pragma unroll
    for (int mi = 0; mi < 4; ++mi) {
      const int rbase = m0 + wr * 64 + mi * 16 + ku * 4;
#pragma unroll
      for (int j = 0; j < 4; ++j) {
        float val = acc[mi][ni][j] + b;
        if constexpr (OM == 0) {
          outS[(size_t)(rbase + j) * HD + n0 + col] = (short)f2bf(val);
        } else if constexpr (OM == 1) {
          val = fmaxf(val, 0.f);
          outS[(size_t)(rbase + j) * HD + n0 + col] = (short)f2bf(val);
        } else {
          outF[(size_t)pg[mi][j] * HD + n0 + col] = val;
        }
      }
    }
  }
}

// ---------------- launch ----------------

extern "C" void kernel_launch(void* const* d_in, const int* in_sizes, int n_in,
                              void* d_out, int out_size, void* d_ws, size_t ws_size,
                              hipStream_t stream) {
  const float* v    = (const float*)d_in[0];
  const float* r    = (const float*)d_in[1];
  const int*   rol  = (const int*)d_in[2];
  const float* W    = (const float*)d_in[3];
  const float* Wb   = (const float*)d_in[4];
  const float* U    = (const float*)d_in[5];
  const float* Ub   = (const float*)d_in[6];
  const float* P1   = (const float*)d_in[7];
  const float* P1b  = (const float*)d_in[8];
  const float* P2   = (const float*)d_in[9];
  const float* P2b  = (const float*)d_in[10];
  const int*   dly  = (const int*)d_in[11];

  char* ws = (char*)d_ws;
  int* ctrl = (int*)ws;                          // 256 B
  int* perm = (int*)(ws + 256);                  // EPAD_MAX ints -> ends 132,864
  short* Wbf = (short*)(ws + 132864);            // 4 x NR*HD*HD bf16
  short* Ubf  = Wbf + (size_t)NR * HD * HD;
  short* P1bf = Ubf + (size_t)NR * HD * HD;
  short* P2bf = P1bf + (size_t)NR * HD * HD;     // ends 6,424,320
  short* rp = (short*)(ws + 6424320);            // EPAD_MAX*HD bf16 -> ends 40,371,968
  short* tb = rp + (size_t)EPAD_MAX * HD;        // ends 74,319,616 (proven ws bound)
  short* vp  = (short*)d_out;                    // d_out front (dead before S3 writes)
  float* out = (float*)d_out;

  k_sort1<<<1, 1024, 0, stream>>>(rol, ctrl);
  k_scatter<<<E_TOT / 256, 256, 0, stream>>>(rol, ctrl, perm);
  k_padfill<<<1, 256, 0, stream>>>(ctrl, perm);
  k_convw<<<dim3((NR * HD * HD) / 4 / 256, 4, 1), 256, 0, stream>>>(W, U, P1, P2, dly, Wbf);

  // S1 paired + fused gather: vp = gather(v)@W^T+wb, rp = gather(r)@U^T+ub
  k_mm<2, 0, 1><<<NB2, 256, 0, stream>>>(v, r, Wbf, Ubf, Wb, Ub,
                                         dly, ctrl, perm, vp, rp, nullptr);
  // S2: tb = relu((vp*rp)@P1^T + b1)   (product reg-staged)
  k_mm<1, 1, 0><<<NB, 256, 0, stream>>>(vp, rp, P1bf, nullptr, P1b, nullptr,
                                        dly, ctrl, perm, tb, nullptr, nullptr);
  // S3: out[perm] = tb@P2^T + b2       (f32 scatter; overwrites all of d_out)
  k_mm<0, 2, 0><<<NB, 256, 0, stream>>>(tb, nullptr, P2bf, nullptr, P2b, nullptr,
                                        dly, ctrl, perm, nullptr, nullptr, out);

  (void)in_sizes; (void)n_in; (void)out_size; (void)ws_size;
}

// Round 18
// 185.725 us; speedup vs baseline: 1.1111x; 1.1111x over previous
//
#include <hip/hip_runtime.h>
#include <cstdint>
#include <cstddef>

#define E_TOT 32768
#define HD    512
#define NR    3
#define EPAD_MAX 33152          // E_TOT + 3*128
#define NTM   259               // EPAD_MAX / 128
#define NB    1036              // NTM * 4 N-tiles (BN=128, S2/S3)
#define NBS1  1036              // NTM * 2 N-tiles (BN=256) * 2 matrices

typedef __attribute__((ext_vector_type(8))) short short8;
typedef __attribute__((ext_vector_type(4))) float f32x4;

static __device__ __forceinline__ unsigned short f2bf(float f) {
  union { float f; unsigned int u; } x; x.f = f;
  unsigned int u = x.u;
  return (unsigned short)((u + 0x7fffu + ((u >> 16) & 1u)) >> 16);  // RNE
}
static __device__ __forceinline__ float bf2f(unsigned short h) {
  union { unsigned int u; float f; } x; x.u = ((unsigned int)h) << 16;
  return x.f;
}

static __device__ __forceinline__ void gload_lds16(const void* g, void* l) {
  __builtin_amdgcn_global_load_lds(
      (const __attribute__((address_space(1))) unsigned int*)g,
      (__attribute__((address_space(3))) unsigned int*)l, 16, 0, 0);
}

// bijective chunked XCD swizzle (m204)
template <int NWG>
static __device__ __forceinline__ int chunk_swz(int bid) {
  constexpr int q = NWG / 8, r = NWG % 8;
  const int x = bid & 7, i = bid >> 3;
  return (x < r) ? x * (q + 1) + i : r * (q + 1) + (x - r) * q + i;
}

// ---------------- prep kernels ----------------

#define AL128(x) (((x) + 127) & ~127)

__global__ void k_sort1(const int* __restrict__ roles, int* __restrict__ ctrl) {
  __shared__ int cnt[NR];
  const int t = threadIdx.x;
  if (t < NR) cnt[t] = 0;
  __syncthreads();
  int c0 = 0, c1 = 0, c2 = 0;
  for (int i = t; i < E_TOT; i += 1024) {
    const int ro = roles[i];
    c0 += (ro == 0); c1 += (ro == 1); c2 += (ro == 2);
  }
  if (c0) atomicAdd(&cnt[0], c0);
  if (c1) atomicAdd(&cnt[1], c1);
  if (c2) atomicAdd(&cnt[2], c2);
  __syncthreads();
  if (t == 0) {
    const int off1 = AL128(cnt[0]);
    const int off2 = AL128(off1 + cnt[1]);
    const int ptot = AL128(off2 + cnt[2]);
    ctrl[0] = cnt[0]; ctrl[1] = cnt[1]; ctrl[2] = cnt[2];
    ctrl[4] = 0; ctrl[5] = off1; ctrl[6] = off2; ctrl[7] = ptot;
    ctrl[9] = 0; ctrl[10] = off1; ctrl[11] = off2;
  }
}

__global__ void k_scatter(const int* __restrict__ roles, int* __restrict__ ctrl,
                          int* __restrict__ perm) {
  int e = blockIdx.x * 256 + threadIdx.x;
  int lane = threadIdx.x & 63;
  int role = roles[e];
#pragma unroll
  for (int r = 0; r < NR; ++r) {
    unsigned long long m = __ballot(role == r);
    if (!m) continue;
    int leader = __ffsll((unsigned long long)m) - 1;
    int base = 0;
    if (lane == leader) base = atomicAdd(&ctrl[9 + r], (int)__popcll(m));
    base = __shfl(base, leader);
    if (role == r) {
      int rank = (int)__popcll(m & ((1ull << lane) - 1ull));
      perm[base + rank] = e;
    }
  }
}

// fill pad slots through EPAD_MAX so every perm read is valid
__global__ void k_padfill(const int* __restrict__ ctrl, int* __restrict__ perm) {
#pragma unroll
  for (int r = 0; r < NR; ++r) {
    const int start = ctrl[4 + r] + ctrl[r];
    const int end = (r < 2) ? ctrl[5 + r] : EPAD_MAX;
    const int fill = (ctrl[r] > 0) ? perm[ctrl[4 + r]] : 0;
    for (int i = start + (int)threadIdx.x; i < end; i += 256) perm[i] = fill;
  }
}

__global__ void k_convw(const float* __restrict__ W, const float* __restrict__ U,
                        const float* __restrict__ P1, const float* __restrict__ P2,
                        const int* __restrict__ dlayer, short* __restrict__ dst) {
  const int per = NR * HD * HD;
  const int which = blockIdx.y;
  const float* src = (which == 0) ? W : (which == 1) ? U : (which == 2) ? P1 : P2;
  src += (size_t)dlayer[0] * per;
  short* d = dst + (size_t)which * per;
  int i = (blockIdx.x * 256 + threadIdx.x) * 4;
  if (i >= per) return;
  float4 v = *(const float4*)(src + i);
  short4 o;
  o.x = (short)f2bf(v.x); o.y = (short)f2bf(v.y);
  o.z = (short)f2bf(v.z); o.w = (short)f2bf(v.w);
  *(short4*)(d + i) = o;
}

// ---------------- S1: fused-gather paired GEMM, BM=128 x BN=256 ----------------
// 512 thr = 8 waves (2M x 4N), wave tile 64x64, acc[4][4]=64 floats (~96 VGPR,
// R14/R16-proven class). LDS 48KB single-buffer -> 2 blocks/CU x 8 waves =
// 16 waves/CU (same TLP as R16). BN=256 halves the f32 A-redundancy (4x -> 2x),
// the dominant S1 traffic term. m97-style 2-barrier loop (R15: dbuf is NULL).
// XOR swizzle u' = u ^ (row&7), pre-swizzled sources (R5: 0-conflict).
// D-frag: col=lane&15, row=(lane>>4)*4+reg [m89/m91-verified].
__global__ __launch_bounds__(512) void k_s1(
    const float* __restrict__ vsrc, const float* __restrict__ rsrc,
    const short* __restrict__ B0, const short* __restrict__ B1,
    const float* __restrict__ bias0, const float* __restrict__ bias1,
    const int* __restrict__ dlayer, const int* __restrict__ ctrl,
    const int* __restrict__ perm, short* __restrict__ vp,
    short* __restrict__ rp) {
  __shared__ short As[128 * 64];   // 16 KB
  __shared__ short Bs[256 * 64];   // 32 KB

  int lb = chunk_swz<NBS1>(blockIdx.x);
  const int pair = lb >= (NTM * 2) ? 1 : 0;
  lb -= pair * (NTM * 2);
  const int m0 = (lb >> 1) * 128, n0 = (lb & 1) * 256;
  if (m0 >= ctrl[7]) return;
  const int role = (m0 >= ctrl[6]) ? 2 : (m0 >= ctrl[5] ? 1 : 0);

  const int tid = threadIdx.x;
  const int lane = tid & 63;
  const int wv = tid >> 6;
  const int wr = wv >> 2, wc = wv & 3;       // 2M x 4N waves
  const int krow = lane & 15, ku = lane >> 4;

  const short* Brole = (pair ? B1 : B0) + (size_t)role * HD * HD;
  const float* Af32 = pair ? rsrc : vsrc;

  // A staging: 1024 units, 2/thread; pre-swizzled gathered f32 source
  unsigned asrc[2];
#pragma unroll
  for (int j = 0; j < 2; ++j) {
    const int g = j * 512 + tid;
    const int row = g >> 3;
    const int ud = (g & 7) ^ (row & 7);
    asrc[j] = (unsigned)perm[m0 + row] * HD + ud * 8;
  }
  // B staging: 2048 units, 4/thread
  unsigned bsrc[4];
#pragma unroll
  for (int j = 0; j < 4; ++j) {
    const int g = j * 512 + tid;
    const int row = g >> 3;
    const int ud = (g & 7) ^ (row & 7);
    bsrc[j] = (unsigned)(n0 + row) * HD + ud * 8;
  }

  f32x4 acc[4][4];
#pragma unroll
  for (int a = 0; a < 4; ++a)
#pragma unroll
    for (int b = 0; b < 4; ++b) acc[a][b] = (f32x4)0.f;

  for (int t = 0; t < 8; ++t) {
    const int k0 = t * 64;
    // ---- stage ----
#pragma unroll
    for (int j = 0; j < 4; ++j)
      gload_lds16(Brole + (size_t)bsrc[j] + k0, &Bs[(j * 512 + tid) * 8]);
#pragma unroll
    for (int j = 0; j < 2; ++j) {
      const float* s = Af32 + (size_t)asrc[j] + k0;
      const float4 x0 = *(const float4*)s;
      const float4 x1 = *(const float4*)(s + 4);
      short8 o;
#pragma unroll
      for (int e = 0; e < 4; ++e) {
        o[e]     = (short)f2bf(((const float*)&x0)[e]);
        o[4 + e] = (short)f2bf(((const float*)&x1)[e]);
      }
      *(short8*)&As[(j * 512 + tid) * 8] = o;
    }
    __syncthreads();   // drains gload_lds + ds_write
    // ---- compute ----
    short8 fa[4][2], fb[4][2];
#pragma unroll
    for (int mi = 0; mi < 4; ++mi)
#pragma unroll
      for (int ks = 0; ks < 2; ++ks) {
        const int row = wr * 64 + mi * 16 + krow;
        fa[mi][ks] = *(const short8*)&As[row * 64 + (((ks * 4 + ku) ^ (row & 7)) * 8)];
      }
#pragma unroll
    for (int ni = 0; ni < 4; ++ni)
#pragma unroll
      for (int ks = 0; ks < 2; ++ks) {
        const int row = wc * 64 + ni * 16 + krow;
        fb[ni][ks] = *(const short8*)&Bs[row * 64 + (((ks * 4 + ku) ^ (row & 7)) * 8)];
      }
#pragma unroll
    for (int ks = 0; ks < 2; ++ks)
#pragma unroll
      for (int mi = 0; mi < 4; ++mi)
#pragma unroll
        for (int ni = 0; ni < 4; ++ni)
          acc[mi][ni] = __builtin_amdgcn_mfma_f32_16x16x32_bf16(
              fa[mi][ks], fb[ni][ks], acc[mi][ni], 0, 0, 0);
    __syncthreads();
  }

  // ---- epilogue: bf16 + bias, direct stores ----
  const int ld = dlayer[0];
  const float* bias = (pair ? bias1 : bias0) + ((size_t)ld * NR + role) * HD + n0;
  short* outS = pair ? rp : vp;

#pragma unroll
  for (int ni = 0; ni < 4; ++ni) {
    const int col = wc * 64 + ni * 16 + krow;
    const float b = bias[col];
#pragma unroll
    for (int mi = 0; mi < 4; ++mi) {
      const int rbase = m0 + wr * 64 + mi * 16 + ku * 4;
#pragma unroll
      for (int j = 0; j < 4; ++j) {
        const float val = acc[mi][ni][j] + b;
        outS[(size_t)(rbase + j) * HD + n0 + col] = (short)f2bf(val);
      }
    }
  }
}

// ---------------- S2/S3: m97-style GEMM (R16 core, 128x128) ----------------
// BM=BN=128, BK=64. 256 thr = 4 waves (2M x 2N), wave tile 64x64.
// acc[4][4]=64 floats, ~96 VGPR no-spill, ~4 blocks/CU (R14-measured).
// AM 0: A bf16 via global_load_lds. AM 1: A = A0*A1 product, reg-staged.
// OM 1: bf16 + bias + relu. OM 2: f32 perm-scatter.
template <int AM, int OM>
__global__ __launch_bounds__(256) void k_mm(
    const short* __restrict__ A0, const short* __restrict__ A1,
    const short* __restrict__ B0, const float* __restrict__ bias0,
    const int* __restrict__ dlayer, const int* __restrict__ ctrl,
    const int* __restrict__ perm, short* __restrict__ outS,
    float* __restrict__ outF) {
  __shared__ short As[128 * 64];
  __shared__ short Bs[128 * 64];

  const int lb = chunk_swz<NB>(blockIdx.x);
  const int m0 = (lb >> 2) * 128, n0 = (lb & 3) * 128;
  if (m0 >= ctrl[7]) return;
  const int role = (m0 >= ctrl[6]) ? 2 : (m0 >= ctrl[5] ? 1 : 0);

  const int tid = threadIdx.x;
  const int lane = tid & 63;
  const int wv = tid >> 6;
  const int wr = wv >> 1, wc = wv & 1;
  const int krow = lane & 15, ku = lane >> 4;

  const short* Brole = B0 + (size_t)role * HD * HD;

  unsigned asrc[4], bsrc[4];
#pragma unroll
  for (int j = 0; j < 4; ++j) {
    const int g = j * 256 + tid;
    const int row = g >> 3;
    const int ud = (g & 7) ^ (row & 7);
    asrc[j] = (unsigned)(m0 + row) * HD + ud * 8;
    bsrc[j] = (unsigned)(n0 + row) * HD + ud * 8;
  }

  f32x4 acc[4][4];
#pragma unroll
  for (int a = 0; a < 4; ++a)
#pragma unroll
    for (int b = 0; b < 4; ++b) acc[a][b] = (f32x4)0.f;

  for (int t = 0; t < 8; ++t) {
    const int k0 = t * 64;
#pragma unroll
    for (int j = 0; j < 4; ++j)
      gload_lds16(Brole + (size_t)bsrc[j] + k0, &Bs[(j * 256 + tid) * 8]);
    if constexpr (AM == 0) {
#pragma unroll
      for (int j = 0; j < 4; ++j)
        gload_lds16(A0 + (size_t)asrc[j] + k0, &As[(j * 256 + tid) * 8]);
    } else {
#pragma unroll
      for (int j = 0; j < 4; ++j) {
        const short8 av = *(const short8*)(A0 + (size_t)asrc[j] + k0);
        const short8 ar = *(const short8*)(A1 + (size_t)asrc[j] + k0);
        short8 o;
#pragma unroll
        for (int e = 0; e < 8; ++e)
          o[e] = (short)f2bf(bf2f((unsigned short)av[e]) *
                             bf2f((unsigned short)ar[e]));
        *(short8*)&As[(j * 256 + tid) * 8] = o;
      }
    }
    __syncthreads();
    short8 fa[4][2], fb[4][2];
#pragma unroll
    for (int mi = 0; mi < 4; ++mi)
#pragma unroll
      for (int ks = 0; ks < 2; ++ks) {
        const int row = wr * 64 + mi * 16 + krow;
        fa[mi][ks] = *(const short8*)&As[row * 64 + (((ks * 4 + ku) ^ (row & 7)) * 8)];
      }
#pragma unroll
    for (int ni = 0; ni < 4; ++ni)
#pragma unroll
      for (int ks = 0; ks < 2; ++ks) {
        const int row = wc * 64 + ni * 16 + krow;
        fb[ni][ks] = *(const short8*)&Bs[row * 64 + (((ks * 4 + ku) ^ (row & 7)) * 8)];
      }
#pragma unroll
    for (int ks = 0; ks < 2; ++ks)
#pragma unroll
      for (int mi = 0; mi < 4; ++mi)
#pragma unroll
        for (int ni = 0; ni < 4; ++ni)
          acc[mi][ni] = __builtin_amdgcn_mfma_f32_16x16x32_bf16(
              fa[mi][ks], fb[ni][ks], acc[mi][ni], 0, 0, 0);
    __syncthreads();
  }

  const int ld = dlayer[0];
  const float* bias = bias0 + ((size_t)ld * NR + role) * HD + n0;

  int pg[4][4];
  if constexpr (OM == 2) {
#pragma unroll
    for (int mi = 0; mi < 4; ++mi)
#pragma unroll
      for (int j = 0; j < 4; ++j)
        pg[mi][j] = perm[m0 + wr * 64 + mi * 16 + ku * 4 + j];
  }

#pragma unroll
  for (int ni = 0; ni < 4; ++ni) {
    const int col = wc * 64 + ni * 16 + krow;
    const float b = bias[col];
#pragma unroll
    for (int mi = 0; mi < 4; ++mi) {
      const int rbase = m0 + wr * 64 + mi * 16 + ku * 4;
#pragma unroll
      for (int j = 0; j < 4; ++j) {
        float val = acc[mi][ni][j] + b;
        if constexpr (OM == 1) {
          val = fmaxf(val, 0.f);
          outS[(size_t)(rbase + j) * HD + n0 + col] = (short)f2bf(val);
        } else {
          outF[(size_t)pg[mi][j] * HD + n0 + col] = val;
        }
      }
    }
  }
}

// ---------------- launch ----------------

extern "C" void kernel_launch(void* const* d_in, const int* in_sizes, int n_in,
                              void* d_out, int out_size, void* d_ws, size_t ws_size,
                              hipStream_t stream) {
  const float* v    = (const float*)d_in[0];
  const float* r    = (const float*)d_in[1];
  const int*   rol  = (const int*)d_in[2];
  const float* W    = (const float*)d_in[3];
  const float* Wb   = (const float*)d_in[4];
  const float* U    = (const float*)d_in[5];
  const float* Ub   = (const float*)d_in[6];
  const float* P1   = (const float*)d_in[7];
  const float* P1b  = (const float*)d_in[8];
  const float* P2   = (const float*)d_in[9];
  const float* P2b  = (const float*)d_in[10];
  const int*   dly  = (const int*)d_in[11];

  char* ws = (char*)d_ws;
  int* ctrl = (int*)ws;                          // 256 B
  int* perm = (int*)(ws + 256);                  // EPAD_MAX ints -> ends 132,864
  short* Wbf = (short*)(ws + 132864);            // 4 x NR*HD*HD bf16
  short* Ubf  = Wbf + (size_t)NR * HD * HD;
  short* P1bf = Ubf + (size_t)NR * HD * HD;
  short* P2bf = P1bf + (size_t)NR * HD * HD;     // ends 6,424,320
  short* rp = (short*)(ws + 6424320);            // EPAD_MAX*HD bf16 -> ends 40,371,968
  short* tb = rp + (size_t)EPAD_MAX * HD;        // ends 74,319,616 (proven ws bound)
  short* vp  = (short*)d_out;                    // d_out front (dead before S3 writes)
  float* out = (float*)d_out;

  k_sort1<<<1, 1024, 0, stream>>>(rol, ctrl);
  k_scatter<<<E_TOT / 256, 256, 0, stream>>>(rol, ctrl, perm);
  k_padfill<<<1, 256, 0, stream>>>(ctrl, perm);
  k_convw<<<dim3((NR * HD * HD) / 4 / 256, 4, 1), 256, 0, stream>>>(W, U, P1, P2, dly, Wbf);

  // S1 paired + fused gather, BN=256: vp = gather(v)@W^T+wb, rp = gather(r)@U^T+ub
  k_s1<<<NBS1, 512, 0, stream>>>(v, r, Wbf, Ubf, Wb, Ub, dly, ctrl, perm, vp, rp);
  // S2: tb = relu((vp*rp)@P1^T + b1)   (product reg-staged)
  k_mm<1, 1><<<NB, 256, 0, stream>>>(vp, rp, P1bf, P1b, dly, ctrl, perm, tb, nullptr);
  // S3: out[perm] = tb@P2^T + b2       (f32 scatter; overwrites all of d_out)
  k_mm<0, 2><<<NB, 256, 0, stream>>>(tb, nullptr, P2bf, P2b, dly, ctrl, perm, nullptr, out);

  (void)in_sizes; (void)n_in; (void)out_size; (void)ws_size;
}